// Round 5
// baseline (307.852 us; speedup 1.0000x reference)
//
#include <hip/hip_runtime.h>

#define T_DEPTH 200000
#define V_DIM   130
#define H_DIM   512

// d_out offsets (fp32 elements): ot, Val, stg, rt, h_new, c_new
#define OT_OFF   0
#define VAL_OFF  512
#define STG_OFF  26000642
#define RT_OFF   26200643
#define HN_OFF   26200773
#define CN_OFF   26201797

// ws offsets (floats) — all written before read, no memset needed
#define WS_DTUT  0
#define WS_H1    64
#define WS_C1    576
#define WS_H2    1088
#define WS_C2    1600

#define NV4 6500000   // T*V/4
#define NS2 100000    // T/2

static __device__ __forceinline__ float sigmoidf_(float x) {
  return 1.0f / (1.0f + expf(-x));
}

// ---- big copy: byte-identical to the verified round-0 k_bulk (61 µs) ----
__global__ void k_bulk(const float4* __restrict__ val_in,
                       const float2* __restrict__ stg_in,
                       float* __restrict__ out) {
  const int NT = NV4 + NS2;
  float4* __restrict__ val_out = reinterpret_cast<float4*>(out + VAL_OFF);
  float2* __restrict__ stg_out = reinterpret_cast<float2*>(out + STG_OFF);
  int stride = gridDim.x * blockDim.x;
  for (int u = blockIdx.x * blockDim.x + threadIdx.x; u < NT; u += stride) {
    if (u < NV4) val_out[u] = val_in[u];
    else { int s = u - NV4; stg_out[s] = stg_in[s]; }
  }
}

// one wave computes all 4 gate dots for unit j, then lane 0 applies the cell.
// (verified in rounds 3-4) x = x_a (+ x_b if non-null)
static __device__ __forceinline__ void lstm_unit(
    const float* __restrict__ Wih, int in_dim,
    const float* __restrict__ x_a, const float* __restrict__ x_b,
    const float* __restrict__ Whh, const float* __restrict__ hprev,
    const float* __restrict__ bih, const float* __restrict__ bhh,
    const float* __restrict__ cprev, int j, int lane,
    float* __restrict__ h_ws, float* __restrict__ c_ws,
    float* __restrict__ h_out, float* __restrict__ c_out) {
  float pg[4];
#pragma unroll
  for (int q = 0; q < 4; ++q) {
    int row = q * H_DIM + j;
    const float* wr = Wih + row * in_dim;
    const float* wh = Whh + row * H_DIM;
    float acc = 0.f;
    if (x_b) {
      for (int c = lane; c < in_dim; c += 64) acc += wr[c] * (x_a[c] + x_b[c]);
    } else {
      for (int c = lane; c < in_dim; c += 64) acc += wr[c] * x_a[c];
    }
    for (int k = lane; k < H_DIM; k += 64) acc += wh[k] * hprev[k];
    for (int off = 32; off; off >>= 1) acc += __shfl_down(acc, off, 64);
    pg[q] = acc;  // total valid on lane 0
  }
  if (lane == 0) {
    float ig = sigmoidf_(pg[0] + bih[j] + bhh[j]);
    float fg = sigmoidf_(pg[1] + bih[H_DIM + j] + bhh[H_DIM + j]);
    float gg = tanhf(pg[2] + bih[2 * H_DIM + j] + bhh[2 * H_DIM + j]);
    float og = sigmoidf_(pg[3] + bih[3 * H_DIM + j] + bhh[3 * H_DIM + j]);
    float cn = fg * cprev[j] + ig * gg;
    float hn = og * tanhf(cn);
    h_ws[j] = hn; c_ws[j] = cn;
    h_out[j] = hn; c_out[j] = cn;
  }
}

// ---- fused layer-0 gates + cell: 128 blocks, wave per unit
__global__ void kL0(const float* __restrict__ Wih, const float* __restrict__ Whh,
                    const float* __restrict__ bih, const float* __restrict__ bhh,
                    const float* __restrict__ inp, const float* __restrict__ prd,
                    const float* __restrict__ hprev, const float* __restrict__ cprev,
                    float* __restrict__ ws, float* __restrict__ out) {
  int j = blockIdx.x * 4 + (threadIdx.x >> 6), lane = threadIdx.x & 63;
  lstm_unit(Wih, V_DIM, inp, prd, Whh, hprev, bih, bhh, cprev, j, lane,
            ws + WS_H1, ws + WS_C1, out + HN_OFF, out + CN_OFF);
}

// ---- fused layer-1 gates + cell
__global__ void kL1(const float* __restrict__ Wih, const float* __restrict__ Whh,
                    const float* __restrict__ bih, const float* __restrict__ bhh,
                    const float* __restrict__ hprev, const float* __restrict__ cprev,
                    float* __restrict__ ws, float* __restrict__ out) {
  int j = blockIdx.x * 4 + (threadIdx.x >> 6), lane = threadIdx.x & 63;
  lstm_unit(Wih, H_DIM, ws + WS_H1, nullptr, Whh, hprev, bih, bhh, cprev, j, lane,
            ws + WS_H2, ws + WS_C2, out + HN_OFF + H_DIM, out + CN_OFF + H_DIM);
}

// ---- fused heads + finalize: 4 blocks, column-owner dots (no atomics)
__global__ void kheads(const float* __restrict__ Wv, const float* __restrict__ Bv,
                       const float* __restrict__ Wo, const float* __restrict__ Bo,
                       const float* __restrict__ Wd, const float* __restrict__ Bd,
                       const float* __restrict__ Wu, const float* __restrict__ Bu,
                       float* __restrict__ ws, float* __restrict__ out) {
  int bid = blockIdx.x, tid = threadIdx.x;
  const float* h2 = ws + WS_H2;
  if (bid < 2) {
    int t = bid * 256 + tid;
    float a0 = 0.f, a1 = 0.f, a2 = 0.f, a3 = 0.f;
    for (int k = 0; k < H_DIM; k += 4) {
      a0 += h2[k]     * Wo[k * H_DIM + t];
      a1 += h2[k + 1] * Wo[(k + 1) * H_DIM + t];
      a2 += h2[k + 2] * Wo[(k + 2) * H_DIM + t];
      a3 += h2[k + 3] * Wo[(k + 3) * H_DIM + t];
    }
    out[OT_OFF + t] = tanhf(((a0 + a1) + (a2 + a3)) + Bo[t]);
  } else if (bid == 2) {
    if (tid < V_DIM) {
      float a0 = 0.f, a1 = 0.f, a2 = 0.f, a3 = 0.f;
      for (int k = 0; k < H_DIM; k += 4) {
        a0 += h2[k]     * Wv[k * V_DIM + tid];
        a1 += h2[k + 1] * Wv[(k + 1) * V_DIM + tid];
        a2 += h2[k + 2] * Wv[(k + 2) * V_DIM + tid];
        a3 += h2[k + 3] * Wv[(k + 3) * V_DIM + tid];
      }
      out[VAL_OFF + T_DEPTH * V_DIM + tid] = tanhf(((a0 + a1) + (a2 + a3)) + Bv[tid]);
    }
  } else {
    int wid = tid >> 6, lane = tid & 63;
    if (wid < 2) {
      const float* wv = (wid == 0) ? Wd : Wu;
      float acc = 0.f;
      for (int k = lane; k < H_DIM; k += 64) acc += h2[k] * wv[k];
      for (int off = 32; off; off >>= 1) acc += __shfl_down(acc, off, 64);
      if (lane == 0) {
        if (wid == 0) {
          float dt = sigmoidf_(acc + Bd[0]);
          ws[WS_DTUT + 0] = dt;
          out[STG_OFF + T_DEPTH] = dt;       // stg[T] = dt
        } else {
          ws[WS_DTUT + 1] = sigmoidf_(acc + Bu[0]);  // ut
        }
      }
    }
  }
}

// ---- exact top-of-stack walk: pop head rewrite + early-terminated rt
__global__ void ktop(const float* __restrict__ prev_stg, const float* __restrict__ prev_val,
                     const float* __restrict__ ws, float* __restrict__ out) {
  int t = threadIdx.x;  // 192
  float dt = ws[WS_DTUT + 0];
  float u  = ws[WS_DTUT + 1];  // pop carry (starts at ut)
  float r  = 1.0f;             // read carry
  float acc = 0.f;
  {  // i = T (freshly pushed row): stg[T]=dt already written, vt in out Val row T
    float coef = fminf(dt, fmaxf(0.f, r));
    if (t < V_DIM) acc += coef * out[VAL_OFF + T_DEPTH * V_DIM + t];
    r -= dt;
  }
  for (int i = T_DEPTH - 1; i >= 0; --i) {
    bool pop_active = (u > 0.f);
    if (!pop_active && r <= 0.f) break;   // below: sn == s (bulk copy correct), coef == 0
    float s  = prev_stg[i];               // wave-uniform load
    float sn = fmaxf(0.f, s - fmaxf(0.f, u));
    u -= sn;
    if (pop_active && t == 0) out[STG_OFF + i] = sn;
    float coef = fminf(sn, fmaxf(0.f, r));
    r -= sn;
    if (coef > 0.f && t < V_DIM) acc += coef * prev_val[i * V_DIM + t];
  }
  if (t < V_DIM) out[RT_OFF + t] = acc;
}

extern "C" void kernel_launch(void* const* d_in, const int* in_sizes, int n_in,
                              void* d_out, int out_size, void* d_ws, size_t ws_size,
                              hipStream_t stream) {
  (void)in_sizes; (void)n_in; (void)out_size; (void)ws_size;
  const float* input     = (const float*)d_in[0];
  const float* prev_Val  = (const float*)d_in[1];
  const float* prev_stg  = (const float*)d_in[2];
  const float* prev_read = (const float*)d_in[3];
  const float* prev_h    = (const float*)d_in[4];
  const float* prev_c    = (const float*)d_in[5];
  const float* W_ih0 = (const float*)d_in[6];
  const float* W_hh0 = (const float*)d_in[7];
  const float* b_ih0 = (const float*)d_in[8];
  const float* b_hh0 = (const float*)d_in[9];
  const float* W_ih1 = (const float*)d_in[10];
  const float* W_hh1 = (const float*)d_in[11];
  const float* b_ih1 = (const float*)d_in[12];
  const float* b_hh1 = (const float*)d_in[13];
  const float* Wd = (const float*)d_in[14];
  const float* Bd = (const float*)d_in[15];
  const float* Wu = (const float*)d_in[16];
  const float* Bu = (const float*)d_in[17];
  const float* Wv = (const float*)d_in[18];
  const float* Bv = (const float*)d_in[19];
  const float* Wo = (const float*)d_in[20];
  const float* Bo = (const float*)d_in[21];

  float* out = (float*)d_out;
  float* ws  = (float*)d_ws;

  // 5 stream ops (was 9): memset dropped (ws slots all write-before-read);
  // g+cell fused per layer; heads+finalize fused. k_bulk byte-identical to
  // the verified round-0 version for a direct counter A/B.
  k_bulk<<<4096, 256, 0, stream>>>((const float4*)prev_Val, (const float2*)prev_stg, out);
  kL0<<<128, 256, 0, stream>>>(W_ih0, W_hh0, b_ih0, b_hh0, input, prev_read,
                               prev_h, prev_c, ws, out);
  kL1<<<128, 256, 0, stream>>>(W_ih1, W_hh1, b_ih1, b_hh1,
                               prev_h + H_DIM, prev_c + H_DIM, ws, out);
  kheads<<<4, 256, 0, stream>>>(Wv, Bv, Wo, Bo, Wd, Bd, Wu, Bu, ws, out);
  ktop<<<1, 192, 0, stream>>>(prev_stg, prev_Val, ws, out);
}